// Round 1
// baseline (8090.424 us; speedup 1.0000x reference)
//
#include <hip/hip_runtime.h>
#include <cstdint>

#define BB 2
#define NN 1024
#define FF 2048
#define CC 80
#define C2 160
#define NB_ 15
#define ROWS_X (BB*FF)   /* 4096 */
#define ROWS_Y (BB*NN)   /* 2048 */
#define NSLOT 128
#define DR 6

// ---------------- conv1: v = in@W0 + (L@in)@W1 + b, + v-stats partials ----------------
__global__ __launch_bounds__(256) void k_conv1(
    const float* __restrict__ inp, const float* __restrict__ L,
    const float* __restrict__ W0, const float* __restrict__ W1,
    const float* __restrict__ bias, float* __restrict__ v,
    float* __restrict__ vstat)
{
  int bx = blockIdx.x;            // 128 = 2 batches x 64 row-blocks
  int b = bx >> 6, rb = bx & 63;
  int row0 = rb * 16;
  __shared__ float red[256][3];
  __shared__ float lx[16][3];
  __shared__ float st[16][2][CC];
  int t = threadIdx.x;
  int rloc = t >> 4, sl = t & 15;
  const float* Lrow = L + ((size_t)b*NN + row0 + rloc) * NN;
  const float* ipb  = inp + (size_t)b*NN*3;
  float a0=0.f,a1=0.f,a2=0.f;
  for (int m = sl; m < NN; m += 16) {
    float lv = Lrow[m];
    a0 = fmaf(lv, ipb[m*3+0], a0);
    a1 = fmaf(lv, ipb[m*3+1], a1);
    a2 = fmaf(lv, ipb[m*3+2], a2);
  }
  red[t][0]=a0; red[t][1]=a1; red[t][2]=a2;
  __syncthreads();
  if (t < 48) {
    int row = t/3, ci = t%3;
    float s=0.f;
    for (int s2=0; s2<16; ++s2) s += red[row*16+s2][ci];
    lx[row][ci]=s;
  }
  __syncthreads();
  for (int o = t; o < 16*CC; o += 256) {
    int row = o/CC, c = o%CC;
    const float* ir = inp + ((size_t)b*NN + row0 + row)*3;
    float val = bias[c];
    #pragma unroll
    for (int ci=0; ci<3; ++ci)
      val += ir[ci]*W0[ci*CC+c] + lx[row][ci]*W1[ci*CC+c];
    v[((size_t)b*NN + row0 + row)*CC + c] = val;
    st[row][0][c] = val;
    st[row][1][c] = val*val;
  }
  __syncthreads();
  if (t < CC) {
    float s=0.f,q=0.f;
    for (int row=0; row<16; ++row){ s+=st[row][0][t]; q+=st[row][1][t]; }
    vstat[(bx*2+0)*CC + t] = s;
    vstat[(bx*2+1)*CC + t] = q;
  }
}

// ---------------- Dirac: y[m,q] = sum_k A[m,k] * x[k,q]   (q = 0..19) ----------------
__global__ __launch_bounds__(256,2) void k_dirac(
    const float* __restrict__ A, const float* __restrict__ x,
    float* __restrict__ y, int M, int K)
{
  int b = blockIdx.y;
  A += (size_t)b*M*K; x += (size_t)b*K*20; y += (size_t)b*M*20;
  __shared__ float xs[64*21];
  int t = threadIdx.x, lane = t & 63, w = t >> 6;
  int row0 = blockIdx.x*(4*DR) + w*DR;
  float acc[DR][20];
  #pragma unroll
  for (int r=0;r<DR;++r)
    #pragma unroll
    for (int q=0;q<20;++q) acc[r][q]=0.f;
  int nchunk = K >> 6;
  for (int kc=0; kc<nchunk; ++kc) {
    __syncthreads();
    #pragma unroll
    for (int i=0;i<5;++i) {
      int idx = t + i*256;
      xs[(idx/20)*21 + (idx%20)] = x[(size_t)kc*1280 + idx];
    }
    __syncthreads();
    float xr[20];
    #pragma unroll
    for (int q=0;q<20;++q) xr[q]=xs[lane*21+q];
    const float* Ap = A + (size_t)row0*K + kc*64 + lane;
    #pragma unroll
    for (int r=0;r<DR;++r) {
      float a = (row0 + r < M) ? Ap[(size_t)r*K] : 0.f;
      #pragma unroll
      for (int q=0;q<20;++q) acc[r][q] = fmaf(a, xr[q], acc[r][q]);
    }
  }
  #pragma unroll
  for (int r=0;r<DR;++r) {
    #pragma unroll
    for (int q=0;q<20;++q) {
      float s = acc[r][q];
      #pragma unroll
      for (int off=32; off; off>>=1) s += __shfl_xor(s, off, 64);
      acc[r][q]=s;
    }
    int row = row0 + r;
    if (lane==0 && row<M) {
      float4* yp = (float4*)(y + (size_t)row*20);
      yp[0] = make_float4(acc[r][0],acc[r][1],acc[r][2],acc[r][3]);
      yp[1] = make_float4(acc[r][4],acc[r][5],acc[r][6],acc[r][7]);
      yp[2] = make_float4(acc[r][8],acc[r][9],acc[r][10],acc[r][11]);
      yp[3] = make_float4(acc[r][12],acc[r][13],acc[r][14],acc[r][15]);
      yp[4] = make_float4(acc[r][16],acc[r][17],acc[r][18],acc[r][19]);
    }
  }
}

// ---------------- stats partials over a [rows][80] array ----------------
__global__ __launch_bounds__(256) void k_stats(
    const float* __restrict__ src, int rows, float* __restrict__ part)
{
  __shared__ float st[3][2][CC];
  int t = threadIdx.x;
  int c = t % CC, rs = t / CC;
  if (t < 240) {
    float s=0.f,q=0.f;
    for (int row = blockIdx.x*3 + rs; row < rows; row += gridDim.x*3) {
      float val = src[(size_t)row*CC + c];
      s += val; q = fmaf(val,val,q);
    }
    st[rs][0][c]=s; st[rs][1][c]=q;
  }
  __syncthreads();
  if (t < CC) {
    part[(blockIdx.x*2+0)*CC+t]=st[0][0][t]+st[1][0][t]+st[2][0][t];
    part[(blockIdx.x*2+1)*CC+t]=st[0][1][t]+st[1][1][t]+st[2][1][t];
  }
}

// ---------------- fused BN(fold)+FC+ELU+residual, + output-stats partials ----------------
__global__ __launch_bounds__(256) void k_fc(
    const float* __restrict__ p1, const float* __restrict__ p2,
    const float* __restrict__ sp1, int ns1,
    const float* __restrict__ sp2, int ns2,
    const float* __restrict__ g, const float* __restrict__ bb,
    const float* __restrict__ W, const float* __restrict__ cb,
    const float* add, float* out,
    float* __restrict__ statout, int rows, float invrows)
{
  __shared__ float Wl[C2*CC];
  __shared__ float ad[2][C2];
  __shared__ float bpl[CC];
  __shared__ float xsh[3][C2];
  __shared__ float st[3][2][CC];
  int t = threadIdx.x;
  if (t < C2) {
    int c = (t<CC)? t : t-CC;
    const float* sp = (t<CC)? sp1 : sp2;
    int ns = (t<CC)? ns1 : ns2;
    float s=0.f,q=0.f;
    for (int i=0;i<ns;++i){ s += sp[(i*2+0)*CC+c]; q += sp[(i*2+1)*CC+c]; }
    float mean = s*invrows;
    float var  = fmaf(-mean, mean, q*invrows);
    float aa   = g[t]*rsqrtf(var + 1e-5f);
    ad[0][t]=aa; ad[1][t]= bb[t] - mean*aa;
  }
  __syncthreads();
  for (int i=t;i<C2*CC;i+=256) Wl[i] = W[i]*ad[0][i/CC];
  if (t < CC) {
    float s = cb[t];
    for (int c2=0;c2<C2;++c2) s = fmaf(ad[1][c2], W[c2*CC+t], s);
    bpl[t]=s;
  }
  __syncthreads();
  int c = t%CC, rs = t/CC;
  bool act = t < 240;
  float ssum=0.f, ssq=0.f;
  for (int r0 = blockIdx.x*3; r0 < rows; r0 += gridDim.x*3) {
    int row = r0 + rs;
    bool ok = act && row < rows;
    if (ok) {
      xsh[rs][c]    = p1[(size_t)row*CC+c];
      xsh[rs][CC+c] = p2[(size_t)row*CC+c];
    }
    __syncthreads();
    if (ok) {
      float acc = bpl[c];
      #pragma unroll 8
      for (int c2=0;c2<C2;++c2) acc = fmaf(xsh[rs][c2], Wl[c2*CC+c], acc);
      acc = acc>0.f ? acc : expm1f(acc);
      acc += add[(size_t)row*CC+c];
      out[(size_t)row*CC+c] = acc;
      ssum += acc; ssq = fmaf(acc,acc,ssq);
    }
    __syncthreads();
  }
  if (act){ st[rs][0][c]=ssum; st[rs][1][c]=ssq; }
  __syncthreads();
  if (t<CC){
    statout[(blockIdx.x*2+0)*CC+t] = st[0][0][t]+st[1][0][t]+st[2][0][t];
    statout[(blockIdx.x*2+1)*CC+t] = st[0][1][t]+st[1][1][t]+st[2][1][t];
  }
}

// ---------------- final: vf = elu(bn1(v2)+bn2(v1)+bn3(v0)) ----------------
__global__ __launch_bounds__(256) void k_final(
    const float* __restrict__ v2, const float* __restrict__ v1, const float* __restrict__ v0,
    const float* __restrict__ s2, const float* __restrict__ s1, const float* __restrict__ s0,
    const float* __restrict__ g1, const float* __restrict__ b1,
    const float* __restrict__ g2, const float* __restrict__ b2,
    const float* __restrict__ g3, const float* __restrict__ b3,
    float* __restrict__ vf)
{
  __shared__ float A[3][CC], D[3][CC];
  int t = threadIdx.x;
  if (t < 240) {
    int set = t/CC, c = t%CC;
    const float* sp  = set==0? s2 : (set==1? s1 : s0);
    const float* gg  = set==0? g1 : (set==1? g2 : g3);
    const float* bbp = set==0? b1 : (set==1? b2 : b3);
    float s=0.f,q=0.f;
    for (int i=0;i<NSLOT;++i){ s+=sp[(i*2+0)*CC+c]; q+=sp[(i*2+1)*CC+c]; }
    float mean = s*(1.f/ROWS_Y);
    float var  = fmaf(-mean,mean,q*(1.f/ROWS_Y));
    float aa   = gg[c]*rsqrtf(var+1e-5f);
    A[set][c]=aa; D[set][c]=bbp[c]-mean*aa;
  }
  __syncthreads();
  for (size_t idx = (size_t)blockIdx.x*256 + t; idx < (size_t)ROWS_Y*CC; idx += (size_t)gridDim.x*256) {
    int c = (int)(idx % CC);
    float val = fmaf(v2[idx],A[0][c],D[0][c]) + fmaf(v1[idx],A[1][c],D[1][c]) + fmaf(v0[idx],A[2][c],D[2][c]);
    vf[idx] = val>0.f? val : expm1f(val);
  }
}

// ---------------- w[b,n] = sum_k mask[b,k] L[b,k,n] ----------------
__global__ __launch_bounds__(256) void k_w(
    const float* __restrict__ mask, const float* __restrict__ L, float* __restrict__ w)
{
  int bx = blockIdx.x;            // 32
  int b = bx >> 4, n0 = (bx & 15) * 64;
  int t = threadIdx.x;
  int ks = t >> 6;
  __shared__ float red[4][64];
  float acc=0.f;
  const float* Lb = L + (size_t)b*NN*NN;
  const float* mb = mask + b*NN;
  int n = n0 + (t & 63);
  for (int k = ks*256; k < ks*256+256; ++k)
    acc = fmaf(mb[k], Lb[(size_t)k*NN + n], acc);
  red[ks][t&63]=acc;
  __syncthreads();
  if (t < 64) w[b*NN + n0 + t] = red[0][t]+red[1][t]+red[2][t]+red[3][t];
}

// ---------------- pooled partials: p1 = sum mask*vf, p2 = sum w*vf ----------------
__global__ __launch_bounds__(256) void k_pool(
    const float* __restrict__ vf, const float* __restrict__ mask,
    const float* __restrict__ w, float* __restrict__ part)
{
  int bx = blockIdx.x;            // 16
  int b = bx >> 3, slab = bx & 7;
  int t = threadIdx.x, c = t%CC, rs = t/CC;
  __shared__ float st[3][2][CC];
  if (t<240) {
    float a1=0.f,a2=0.f;
    for (int r = rs; r < 128; r += 3) {
      int row = slab*128 + r;
      float val = vf[((size_t)b*NN + row)*CC + c];
      a1 = fmaf(mask[b*NN+row], val, a1);
      a2 = fmaf(w[b*NN+row],    val, a2);
    }
    st[rs][0][c]=a1; st[rs][1][c]=a2;
  }
  __syncthreads();
  if (t<CC) {
    part[((b*8+slab)*2+0)*CC+t] = st[0][0][t]+st[1][0][t]+st[2][0][t];
    part[((b*8+slab)*2+1)*CC+t] = st[0][1][t]+st[1][1][t]+st[2][1][t];
  }
}

// ---------------- out[b,co] = (p1@W0 + p2@W1)/msum + b2 ----------------
__global__ __launch_bounds__(256) void k_out(
    const float* __restrict__ part, const float* __restrict__ mask,
    const float* __restrict__ W0, const float* __restrict__ W1,
    const float* __restrict__ b2, float* __restrict__ outp)
{
  __shared__ float pl[2][2][CC];
  __shared__ float ms[2];
  int t = threadIdx.x;
  if (t < 160) {
    int b = t/CC, c = t%CC;
    float s1=0.f,s2=0.f;
    for (int slab=0; slab<8; ++slab){
      s1 += part[((b*8+slab)*2+0)*CC+c];
      s2 += part[((b*8+slab)*2+1)*CC+c];
    }
    pl[b][0][c]=s1; pl[b][1][c]=s2;
  }
  if (t>=160 && t<162) {
    int b=t-160; float s=0.f;
    for (int k=0;k<NN;++k) s += mask[b*NN+k];
    ms[b]=s;
  }
  __syncthreads();
  int b = t >> 7, co = t & 127;
  float acc = 0.f;
  #pragma unroll 8
  for (int c=0;c<CC;++c)
    acc += pl[b][0][c]*W0[c*128+co] + pl[b][1][c]*W1[c*128+co];
  outp[t] = acc/ms[b] + b2[co];
}

extern "C" void kernel_launch(void* const* d_in, const int* in_sizes, int n_in,
                              void* d_out, int out_size, void* d_ws, size_t ws_size,
                              hipStream_t stream)
{
  const float* inp  = (const float*)d_in[0];
  const float* L    = (const float*)d_in[1];
  const float* Di   = (const float*)d_in[2];
  const float* DiA  = (const float*)d_in[3];
  const float* mask = (const float*)d_in[4];
  const float* c1W0 = (const float*)d_in[5];
  const float* c1W1 = (const float*)d_in[6];
  const float* c1b  = (const float*)d_in[7];
  const float* bn0g = (const float*)d_in[8];
  const float* bn0b = (const float*)d_in[9];
  const float* fc0W = (const float*)d_in[10];
  const float* fc0b = (const float*)d_in[11];
  const float* bn1g = (const float*)d_in[12];
  const float* bn1b = (const float*)d_in[13];
  const float* fc1W = (const float*)d_in[14];
  const float* fc1b = (const float*)d_in[15];
  const float* fbn1g= (const float*)d_in[16];
  const float* fbn1b= (const float*)d_in[17];
  const float* fbn2g= (const float*)d_in[18];
  const float* fbn2b= (const float*)d_in[19];
  const float* fbn3g= (const float*)d_in[20];
  const float* fbn3b= (const float*)d_in[21];
  const float* c2W0 = (const float*)d_in[22];
  const float* c2W1 = (const float*)d_in[23];
  const float* c2b  = (const float*)d_in[24];

  float* ws = (float*)d_ws;
  size_t off = 0;
  auto alloc = [&](size_t n)->float* { float* p = ws + off; off += (n + 63) & ~(size_t)63; return p; };
  float* vb[3];   for (int i=0;i<3;++i) vb[i]   = alloc((size_t)BB*NN*CC);
  float* fb[2];   for (int i=0;i<2;++i) fb[i]   = alloc((size_t)BB*FF*CC);
  float* Dv       = alloc((size_t)BB*FF*CC);
  float* Df       = alloc((size_t)BB*NN*CC);
  float* vstat[3];for (int i=0;i<3;++i) vstat[i]= alloc((size_t)NSLOT*2*CC);
  float* fstat[2];for (int i=0;i<2;++i) fstat[i]= alloc((size_t)NSLOT*2*CC);
  float* dvstat   = alloc((size_t)NSLOT*2*CC);
  float* dfstat   = alloc((size_t)NSLOT*2*CC);
  float* vf       = alloc((size_t)BB*NN*CC);
  float* wv       = alloc((size_t)BB*NN);
  float* part     = alloc((size_t)16*2*CC);

  hipMemsetAsync(fb[0],    0, (size_t)BB*FF*CC*4, stream);
  hipMemsetAsync(fb[1],    0, (size_t)BB*FF*CC*4, stream);
  hipMemsetAsync(vb[1],    0, (size_t)BB*NN*CC*4, stream);
  hipMemsetAsync(fstat[0], 0, (size_t)NSLOT*2*CC*4, stream);

  k_conv1<<<128,256,0,stream>>>(inp, L, c1W0, c1W1, c1b, vb[0], vstat[0]);

  int cur=0, p1=1, p2=2, fcur=0, fs=0;
  for (int it=0; it<NB_; ++it) {
    k_dirac<<<dim3(342,2),256,0,stream>>>(Di, vb[cur], Dv, 4*FF, 4*NN);
    k_stats<<<128,256,0,stream>>>(Dv, ROWS_X, dvstat);
    k_fc<<<128,256,0,stream>>>(fb[fcur], Dv, fstat[fs],NSLOT, dvstat,NSLOT,
        bn0g+(size_t)it*C2, bn0b+(size_t)it*C2, fc0W+(size_t)it*C2*CC, fc0b+(size_t)it*CC,
        fb[1-fcur], fb[1-fcur], fstat[1-fs], ROWS_X, 1.f/ROWS_X);
    fcur = 1-fcur; fs = 1-fs;
    k_dirac<<<dim3(171,2),256,0,stream>>>(DiA, fb[fcur], Df, 4*NN, 4*FF);
    k_stats<<<128,256,0,stream>>>(Df, ROWS_Y, dfstat);
    k_fc<<<128,256,0,stream>>>(vb[cur], Df, vstat[cur],NSLOT, dfstat,NSLOT,
        bn1g+(size_t)it*C2, bn1b+(size_t)it*C2, fc1W+(size_t)it*C2*CC, fc1b+(size_t)it*CC,
        vb[p1], vb[p2], vstat[p2], ROWS_Y, 1.f/ROWS_Y);
    int tmp=p2; p2=p1; p1=cur; cur=tmp;
  }

  k_final<<<128,256,0,stream>>>(vb[cur],vb[p1],vb[p2], vstat[cur],vstat[p1],vstat[p2],
      fbn1g,fbn1b,fbn2g,fbn2b,fbn3g,fbn3b, vf);
  k_w<<<32,256,0,stream>>>(mask, L, wv);
  k_pool<<<16,256,0,stream>>>(vf, mask, wv, part);
  k_out<<<1,256,0,stream>>>(part, mask, c2W0, c2W1, c2b, (float*)d_out);
}

// Round 2
// 7097.302 us; speedup vs baseline: 1.1399x; 1.1399x over previous
//
#include <hip/hip_runtime.h>
#include <cstdint>

#define BB 2
#define NN 1024
#define FF 2048
#define CC 80
#define C2 160
#define NB_ 15
#define ROWS_X (BB*FF)   /* 4096 */
#define ROWS_Y (BB*NN)   /* 2048 */
#define NSLOT 128

// ---------------- conv1: v = in@W0 + (L@in)@W1 + b, + v-stats partials ----------------
__global__ __launch_bounds__(256) void k_conv1(
    const float* __restrict__ inp, const float* __restrict__ L,
    const float* __restrict__ W0, const float* __restrict__ W1,
    const float* __restrict__ bias, float* __restrict__ v,
    float* __restrict__ vstat)
{
  int bx = blockIdx.x;            // 128 = 2 batches x 64 row-blocks
  int b = bx >> 6, rb = bx & 63;
  int row0 = rb * 16;
  __shared__ float red[256][3];
  __shared__ float lx[16][3];
  __shared__ float st[16][2][CC];
  int t = threadIdx.x;
  int rloc = t >> 4, sl = t & 15;
  const float* Lrow = L + ((size_t)b*NN + row0 + rloc) * NN;
  const float* ipb  = inp + (size_t)b*NN*3;
  float a0=0.f,a1=0.f,a2=0.f;
  for (int m = sl; m < NN; m += 16) {
    float lv = Lrow[m];
    a0 = fmaf(lv, ipb[m*3+0], a0);
    a1 = fmaf(lv, ipb[m*3+1], a1);
    a2 = fmaf(lv, ipb[m*3+2], a2);
  }
  red[t][0]=a0; red[t][1]=a1; red[t][2]=a2;
  __syncthreads();
  if (t < 48) {
    int row = t/3, ci = t%3;
    float s=0.f;
    for (int s2=0; s2<16; ++s2) s += red[row*16+s2][ci];
    lx[row][ci]=s;
  }
  __syncthreads();
  for (int o = t; o < 16*CC; o += 256) {
    int row = o/CC, c = o%CC;
    const float* ir = inp + ((size_t)b*NN + row0 + row)*3;
    float val = bias[c];
    #pragma unroll
    for (int ci=0; ci<3; ++ci)
      val += ir[ci]*W0[ci*CC+c] + lx[row][ci]*W1[ci*CC+c];
    v[((size_t)b*NN + row0 + row)*CC + c] = val;
    st[row][0][c] = val;
    st[row][1][c] = val*val;
  }
  __syncthreads();
  if (t < CC) {
    float s=0.f,q=0.f;
    for (int row=0; row<16; ++row){ s+=st[row][0][t]; q+=st[row][1][t]; }
    vstat[(bx*2+0)*CC + t] = s;
    vstat[(bx*2+1)*CC + t] = q;
  }
}

// ---------------- Dirac: y[m,q] = sum_k A[m,k] * x[k,q]  (q=0..19) ----------------
// Pipelined float4 streamer. Chunk = 256 k. xs staged transposed [q][k] so
// compute reads are conflict-free ds_read_b128. DR rows per wave; grid sized
// for exactly 2 blocks/CU (512 blocks) with no tail.
template<int DR>
__global__ __launch_bounds__(256,2) void k_dirac(
    const float* __restrict__ A, const float* __restrict__ x,
    float* __restrict__ y, int M, int K)
{
  int b = blockIdx.y;
  A += (size_t)b*M*K; x += (size_t)b*K*20; y += (size_t)b*M*20;
  __shared__ float xs[2][20][256];
  int t = threadIdx.x, lane = t & 63, w = t >> 6;
  int row0 = blockIdx.x*(4*DR) + w*DR;
  float acc[DR][20];
  #pragma unroll
  for (int r=0;r<DR;++r)
    #pragma unroll
    for (int q=0;q<20;++q) acc[r][q]=0.f;

  const float4* xv = (const float4*)x;   // x row k = 5 float4s at k*5
  int nchunk = K >> 8;

  { // stage chunk 0 (transposed)
    float4 s0[5];
    #pragma unroll
    for (int i=0;i<5;++i) s0[i] = xv[(size_t)t*5 + i];
    #pragma unroll
    for (int i=0;i<5;++i) {
      xs[0][4*i+0][t]=s0[i].x; xs[0][4*i+1][t]=s0[i].y;
      xs[0][4*i+2][t]=s0[i].z; xs[0][4*i+3][t]=s0[i].w;
    }
  }
  __syncthreads();

  for (int c=0; c<nchunk; ++c) {
    int cur = c & 1;
    bool more = (c+1 < nchunk);
    float4 st[5];
    if (more) {                           // issue next x-stage loads early
      size_t kb = (size_t)(c+1)*256 + t;
      #pragma unroll
      for (int i=0;i<5;++i) st[i] = xv[kb*5 + i];
    }
    float4 a4[DR];                        // A loads for this chunk
    const float* Ab = A + (size_t)row0*K + c*256 + (lane<<2);
    #pragma unroll
    for (int r=0;r<DR;++r) a4[r] = *(const float4*)(Ab + (size_t)r*K);
    #pragma unroll
    for (int q=0;q<20;++q) {
      float4 xq = *(const float4*)(&xs[cur][q][lane<<2]);
      #pragma unroll
      for (int r=0;r<DR;++r) {
        acc[r][q] = fmaf(a4[r].x, xq.x, acc[r][q]);
        acc[r][q] = fmaf(a4[r].y, xq.y, acc[r][q]);
        acc[r][q] = fmaf(a4[r].z, xq.z, acc[r][q]);
        acc[r][q] = fmaf(a4[r].w, xq.w, acc[r][q]);
      }
    }
    if (more) {                           // publish next buffer
      #pragma unroll
      for (int i=0;i<5;++i) {
        xs[cur^1][4*i+0][t]=st[i].x; xs[cur^1][4*i+1][t]=st[i].y;
        xs[cur^1][4*i+2][t]=st[i].z; xs[cur^1][4*i+3][t]=st[i].w;
      }
    }
    __syncthreads();
  }

  #pragma unroll
  for (int r=0;r<DR;++r) {
    #pragma unroll
    for (int q=0;q<20;++q) {
      float s = acc[r][q];
      #pragma unroll
      for (int off=32; off; off>>=1) s += __shfl_xor(s, off, 64);
      acc[r][q]=s;
    }
    if (lane==0) {
      float4* yp = (float4*)(y + (size_t)(row0+r)*20);
      yp[0] = make_float4(acc[r][0],acc[r][1],acc[r][2],acc[r][3]);
      yp[1] = make_float4(acc[r][4],acc[r][5],acc[r][6],acc[r][7]);
      yp[2] = make_float4(acc[r][8],acc[r][9],acc[r][10],acc[r][11]);
      yp[3] = make_float4(acc[r][12],acc[r][13],acc[r][14],acc[r][15]);
      yp[4] = make_float4(acc[r][16],acc[r][17],acc[r][18],acc[r][19]);
    }
  }
}

// ---------------- stats partials over a [rows][80] array ----------------
__global__ __launch_bounds__(256) void k_stats(
    const float* __restrict__ src, int rows, float* __restrict__ part)
{
  __shared__ float st[3][2][CC];
  int t = threadIdx.x;
  int c = t % CC, rs = t / CC;
  if (t < 240) {
    float s=0.f,q=0.f;
    for (int row = blockIdx.x*3 + rs; row < rows; row += gridDim.x*3) {
      float val = src[(size_t)row*CC + c];
      s += val; q = fmaf(val,val,q);
    }
    st[rs][0][c]=s; st[rs][1][c]=q;
  }
  __syncthreads();
  if (t < CC) {
    part[(blockIdx.x*2+0)*CC+t]=st[0][0][t]+st[1][0][t]+st[2][0][t];
    part[(blockIdx.x*2+1)*CC+t]=st[0][1][t]+st[1][1][t]+st[2][1][t];
  }
}

// ---------------- fused BN(fold)+FC+ELU+residual, + output-stats partials ----------------
__global__ __launch_bounds__(256) void k_fc(
    const float* __restrict__ p1, const float* __restrict__ p2,
    const float* __restrict__ sp1, int ns1,
    const float* __restrict__ sp2, int ns2,
    const float* __restrict__ g, const float* __restrict__ bb,
    const float* __restrict__ W, const float* __restrict__ cb,
    const float* add, float* out,
    float* __restrict__ statout, int rows, float invrows)
{
  __shared__ float Wl[C2*CC];
  __shared__ float ad[2][C2];
  __shared__ float bpl[CC];
  __shared__ float xsh[3][C2];
  __shared__ float st[3][2][CC];
  int t = threadIdx.x;
  if (t < C2) {
    int c = (t<CC)? t : t-CC;
    const float* sp = (t<CC)? sp1 : sp2;
    int ns = (t<CC)? ns1 : ns2;
    float s=0.f,q=0.f;
    for (int i=0;i<ns;++i){ s += sp[(i*2+0)*CC+c]; q += sp[(i*2+1)*CC+c]; }
    float mean = s*invrows;
    float var  = fmaf(-mean, mean, q*invrows);
    float aa   = g[t]*rsqrtf(var + 1e-5f);
    ad[0][t]=aa; ad[1][t]= bb[t] - mean*aa;
  }
  __syncthreads();
  for (int i=t;i<C2*CC;i+=256) Wl[i] = W[i]*ad[0][i/CC];
  if (t < CC) {
    float s = cb[t];
    for (int c2=0;c2<C2;++c2) s = fmaf(ad[1][c2], W[c2*CC+t], s);
    bpl[t]=s;
  }
  __syncthreads();
  int c = t%CC, rs = t/CC;
  bool act = t < 240;
  float ssum=0.f, ssq=0.f;
  for (int r0 = blockIdx.x*3; r0 < rows; r0 += gridDim.x*3) {
    int row = r0 + rs;
    bool ok = act && row < rows;
    if (ok) {
      xsh[rs][c]    = p1[(size_t)row*CC+c];
      xsh[rs][CC+c] = p2[(size_t)row*CC+c];
    }
    __syncthreads();
    if (ok) {
      float acc = bpl[c];
      #pragma unroll 8
      for (int c2=0;c2<C2;++c2) acc = fmaf(xsh[rs][c2], Wl[c2*CC+c], acc);
      acc = acc>0.f ? acc : expm1f(acc);
      acc += add[(size_t)row*CC+c];
      out[(size_t)row*CC+c] = acc;
      ssum += acc; ssq = fmaf(acc,acc,ssq);
    }
    __syncthreads();
  }
  if (act){ st[rs][0][c]=ssum; st[rs][1][c]=ssq; }
  __syncthreads();
  if (t<CC){
    statout[(blockIdx.x*2+0)*CC+t] = st[0][0][t]+st[1][0][t]+st[2][0][t];
    statout[(blockIdx.x*2+1)*CC+t] = st[0][1][t]+st[1][1][t]+st[2][1][t];
  }
}

// ---------------- final: vf = elu(bn1(v2)+bn2(v1)+bn3(v0)) ----------------
__global__ __launch_bounds__(256) void k_final(
    const float* __restrict__ v2, const float* __restrict__ v1, const float* __restrict__ v0,
    const float* __restrict__ s2, const float* __restrict__ s1, const float* __restrict__ s0,
    const float* __restrict__ g1, const float* __restrict__ b1,
    const float* __restrict__ g2, const float* __restrict__ b2,
    const float* __restrict__ g3, const float* __restrict__ b3,
    float* __restrict__ vf)
{
  __shared__ float A[3][CC], D[3][CC];
  int t = threadIdx.x;
  if (t < 240) {
    int set = t/CC, c = t%CC;
    const float* sp  = set==0? s2 : (set==1? s1 : s0);
    const float* gg  = set==0? g1 : (set==1? g2 : g3);
    const float* bbp = set==0? b1 : (set==1? b2 : b3);
    float s=0.f,q=0.f;
    for (int i=0;i<NSLOT;++i){ s+=sp[(i*2+0)*CC+c]; q+=sp[(i*2+1)*CC+c]; }
    float mean = s*(1.f/ROWS_Y);
    float var  = fmaf(-mean,mean,q*(1.f/ROWS_Y));
    float aa   = gg[c]*rsqrtf(var+1e-5f);
    A[set][c]=aa; D[set][c]=bbp[c]-mean*aa;
  }
  __syncthreads();
  for (size_t idx = (size_t)blockIdx.x*256 + t; idx < (size_t)ROWS_Y*CC; idx += (size_t)gridDim.x*256) {
    int c = (int)(idx % CC);
    float val = fmaf(v2[idx],A[0][c],D[0][c]) + fmaf(v1[idx],A[1][c],D[1][c]) + fmaf(v0[idx],A[2][c],D[2][c]);
    vf[idx] = val>0.f? val : expm1f(val);
  }
}

// ---------------- w[b,n] = sum_k mask[b,k] L[b,k,n] ----------------
__global__ __launch_bounds__(256) void k_w(
    const float* __restrict__ mask, const float* __restrict__ L, float* __restrict__ w)
{
  int bx = blockIdx.x;            // 32
  int b = bx >> 4, n0 = (bx & 15) * 64;
  int t = threadIdx.x;
  int ks = t >> 6;
  __shared__ float red[4][64];
  float acc=0.f;
  const float* Lb = L + (size_t)b*NN*NN;
  const float* mb = mask + b*NN;
  int n = n0 + (t & 63);
  for (int k = ks*256; k < ks*256+256; ++k)
    acc = fmaf(mb[k], Lb[(size_t)k*NN + n], acc);
  red[ks][t&63]=acc;
  __syncthreads();
  if (t < 64) w[b*NN + n0 + t] = red[0][t]+red[1][t]+red[2][t]+red[3][t];
}

// ---------------- pooled partials: p1 = sum mask*vf, p2 = sum w*vf ----------------
__global__ __launch_bounds__(256) void k_pool(
    const float* __restrict__ vf, const float* __restrict__ mask,
    const float* __restrict__ w, float* __restrict__ part)
{
  int bx = blockIdx.x;            // 16
  int b = bx >> 3, slab = bx & 7;
  int t = threadIdx.x, c = t%CC, rs = t/CC;
  __shared__ float st[3][2][CC];
  if (t<240) {
    float a1=0.f,a2=0.f;
    for (int r = rs; r < 128; r += 3) {
      int row = slab*128 + r;
      float val = vf[((size_t)b*NN + row)*CC + c];
      a1 = fmaf(mask[b*NN+row], val, a1);
      a2 = fmaf(w[b*NN+row],    val, a2);
    }
    st[rs][0][c]=a1; st[rs][1][c]=a2;
  }
  __syncthreads();
  if (t<CC) {
    part[((b*8+slab)*2+0)*CC+t] = st[0][0][t]+st[1][0][t]+st[2][0][t];
    part[((b*8+slab)*2+1)*CC+t] = st[0][1][t]+st[1][1][t]+st[2][1][t];
  }
}

// ---------------- out[b,co] = (p1@W0 + p2@W1)/msum + b2 ----------------
__global__ __launch_bounds__(256) void k_out(
    const float* __restrict__ part, const float* __restrict__ mask,
    const float* __restrict__ W0, const float* __restrict__ W1,
    const float* __restrict__ b2, float* __restrict__ outp)
{
  __shared__ float pl[2][2][CC];
  __shared__ float ms[2];
  int t = threadIdx.x;
  if (t < 160) {
    int b = t/CC, c = t%CC;
    float s1=0.f,s2=0.f;
    for (int slab=0; slab<8; ++slab){
      s1 += part[((b*8+slab)*2+0)*CC+c];
      s2 += part[((b*8+slab)*2+1)*CC+c];
    }
    pl[b][0][c]=s1; pl[b][1][c]=s2;
  }
  if (t>=160 && t<162) {
    int b=t-160; float s=0.f;
    for (int k=0;k<NN;++k) s += mask[b*NN+k];
    ms[b]=s;
  }
  __syncthreads();
  int b = t >> 7, co = t & 127;
  float acc = 0.f;
  #pragma unroll 8
  for (int c=0;c<CC;++c)
    acc += pl[b][0][c]*W0[c*128+co] + pl[b][1][c]*W1[c*128+co];
  outp[t] = acc/ms[b] + b2[co];
}

extern "C" void kernel_launch(void* const* d_in, const int* in_sizes, int n_in,
                              void* d_out, int out_size, void* d_ws, size_t ws_size,
                              hipStream_t stream)
{
  const float* inp  = (const float*)d_in[0];
  const float* L    = (const float*)d_in[1];
  const float* Di   = (const float*)d_in[2];
  const float* DiA  = (const float*)d_in[3];
  const float* mask = (const float*)d_in[4];
  const float* c1W0 = (const float*)d_in[5];
  const float* c1W1 = (const float*)d_in[6];
  const float* c1b  = (const float*)d_in[7];
  const float* bn0g = (const float*)d_in[8];
  const float* bn0b = (const float*)d_in[9];
  const float* fc0W = (const float*)d_in[10];
  const float* fc0b = (const float*)d_in[11];
  const float* bn1g = (const float*)d_in[12];
  const float* bn1b = (const float*)d_in[13];
  const float* fc1W = (const float*)d_in[14];
  const float* fc1b = (const float*)d_in[15];
  const float* fbn1g= (const float*)d_in[16];
  const float* fbn1b= (const float*)d_in[17];
  const float* fbn2g= (const float*)d_in[18];
  const float* fbn2b= (const float*)d_in[19];
  const float* fbn3g= (const float*)d_in[20];
  const float* fbn3b= (const float*)d_in[21];
  const float* c2W0 = (const float*)d_in[22];
  const float* c2W1 = (const float*)d_in[23];
  const float* c2b  = (const float*)d_in[24];

  float* ws = (float*)d_ws;
  size_t off = 0;
  auto alloc = [&](size_t n)->float* { float* p = ws + off; off += (n + 63) & ~(size_t)63; return p; };
  float* vb[3];   for (int i=0;i<3;++i) vb[i]   = alloc((size_t)BB*NN*CC);
  float* fb[2];   for (int i=0;i<2;++i) fb[i]   = alloc((size_t)BB*FF*CC);
  float* Dv       = alloc((size_t)BB*FF*CC);
  float* Df       = alloc((size_t)BB*NN*CC);
  float* vstat[3];for (int i=0;i<3;++i) vstat[i]= alloc((size_t)NSLOT*2*CC);
  float* fstat[2];for (int i=0;i<2;++i) fstat[i]= alloc((size_t)NSLOT*2*CC);
  float* dvstat   = alloc((size_t)NSLOT*2*CC);
  float* dfstat   = alloc((size_t)NSLOT*2*CC);
  float* vf       = alloc((size_t)BB*NN*CC);
  float* wv       = alloc((size_t)BB*NN);
  float* part     = alloc((size_t)16*2*CC);

  hipMemsetAsync(fb[0],    0, (size_t)BB*FF*CC*4, stream);
  hipMemsetAsync(fb[1],    0, (size_t)BB*FF*CC*4, stream);
  hipMemsetAsync(vb[1],    0, (size_t)BB*NN*CC*4, stream);
  hipMemsetAsync(fstat[0], 0, (size_t)NSLOT*2*CC*4, stream);

  k_conv1<<<128,256,0,stream>>>(inp, L, c1W0, c1W1, c1b, vb[0], vstat[0]);

  int cur=0, p1=1, p2=2, fcur=0, fs=0;
  for (int it=0; it<NB_; ++it) {
    k_dirac<8><<<dim3(256,2),256,0,stream>>>(Di, vb[cur], Dv, 4*FF, 4*NN);
    k_stats<<<128,256,0,stream>>>(Dv, ROWS_X, dvstat);
    k_fc<<<128,256,0,stream>>>(fb[fcur], Dv, fstat[fs],NSLOT, dvstat,NSLOT,
        bn0g+(size_t)it*C2, bn0b+(size_t)it*C2, fc0W+(size_t)it*C2*CC, fc0b+(size_t)it*CC,
        fb[1-fcur], fb[1-fcur], fstat[1-fs], ROWS_X, 1.f/ROWS_X);
    fcur = 1-fcur; fs = 1-fs;
    k_dirac<4><<<dim3(256,2),256,0,stream>>>(DiA, fb[fcur], Df, 4*NN, 4*FF);
    k_stats<<<128,256,0,stream>>>(Df, ROWS_Y, dfstat);
    k_fc<<<128,256,0,stream>>>(vb[cur], Df, vstat[cur],NSLOT, dfstat,NSLOT,
        bn1g+(size_t)it*C2, bn1b+(size_t)it*C2, fc1W+(size_t)it*C2*CC, fc1b+(size_t)it*CC,
        vb[p1], vb[p2], vstat[p2], ROWS_Y, 1.f/ROWS_Y);
    int tmp=p2; p2=p1; p1=cur; cur=tmp;
  }

  k_final<<<128,256,0,stream>>>(vb[cur],vb[p1],vb[p2], vstat[cur],vstat[p1],vstat[p2],
      fbn1g,fbn1b,fbn2g,fbn2b,fbn3g,fbn3b, vf);
  k_w<<<32,256,0,stream>>>(mask, L, wv);
  k_pool<<<16,256,0,stream>>>(vf, mask, wv, part);
  k_out<<<1,256,0,stream>>>(part, mask, c2W0, c2W1, c2b, (float*)d_out);
}

// Round 3
// 4828.262 us; speedup vs baseline: 1.6756x; 1.4699x over previous
//
#include <hip/hip_runtime.h>
#include <cstdint>

#define BB 2
#define NN 1024
#define FF 2048
#define CC 80
#define C2 160
#define NB_ 15
#define ROWS_X (BB*FF)   /* 4096 */
#define ROWS_Y (BB*NN)   /* 2048 */
#define NSLOT 128

// ---------------- conv1: v = in@W0 + (L@in)@W1 + b, + v-stats partials ----------------
__global__ __launch_bounds__(256) void k_conv1(
    const float* __restrict__ inp, const float* __restrict__ L,
    const float* __restrict__ W0, const float* __restrict__ W1,
    const float* __restrict__ bias, float* __restrict__ v,
    float* __restrict__ vstat)
{
  int bx = blockIdx.x;            // 128 = 2 batches x 64 row-blocks
  int b = bx >> 6, rb = bx & 63;
  int row0 = rb * 16;
  __shared__ float red[256][3];
  __shared__ float lx[16][3];
  __shared__ float st[16][2][CC];
  int t = threadIdx.x;
  int rloc = t >> 4, sl = t & 15;
  const float* Lrow = L + ((size_t)b*NN + row0 + rloc) * NN;
  const float* ipb  = inp + (size_t)b*NN*3;
  float a0=0.f,a1=0.f,a2=0.f;
  for (int m = sl; m < NN; m += 16) {
    float lv = Lrow[m];
    a0 = fmaf(lv, ipb[m*3+0], a0);
    a1 = fmaf(lv, ipb[m*3+1], a1);
    a2 = fmaf(lv, ipb[m*3+2], a2);
  }
  red[t][0]=a0; red[t][1]=a1; red[t][2]=a2;
  __syncthreads();
  if (t < 48) {
    int row = t/3, ci = t%3;
    float s=0.f;
    for (int s2=0; s2<16; ++s2) s += red[row*16+s2][ci];
    lx[row][ci]=s;
  }
  __syncthreads();
  for (int o = t; o < 16*CC; o += 256) {
    int row = o/CC, c = o%CC;
    const float* ir = inp + ((size_t)b*NN + row0 + row)*3;
    float val = bias[c];
    #pragma unroll
    for (int ci=0; ci<3; ++ci)
      val += ir[ci]*W0[ci*CC+c] + lx[row][ci]*W1[ci*CC+c];
    v[((size_t)b*NN + row0 + row)*CC + c] = val;
    st[row][0][c] = val;
    st[row][1][c] = val*val;
  }
  __syncthreads();
  if (t < CC) {
    float s=0.f,q=0.f;
    for (int row=0; row<16; ++row){ s+=st[row][0][t]; q+=st[row][1][t]; }
    vstat[(bx*2+0)*CC + t] = s;
    vstat[(bx*2+1)*CC + t] = q;
  }
}

// ---------------- Dirac: y[m,q] = sum_k A[m,k] * x[k,q]  (q=0..19) ----------------
// Pipelined float4 streamer, DR=4 rows/wave (fits register file: acc 80 +
// prefetch ~56 + addressing < 256 combined -> no scratch spill).
// xs staged transposed [q][k]: conflict-free ds_read_b128 on compute,
// conflict-free ds_write_b32 on stage. A prefetched one chunk ahead.
template<int DR>
__global__ __launch_bounds__(256,2) void k_dirac(
    const float* __restrict__ A, const float* __restrict__ x,
    float* __restrict__ y, int M, int K)
{
  int b = blockIdx.y;
  A += (size_t)b*M*K; x += (size_t)b*K*20; y += (size_t)b*M*20;
  __shared__ float xs[2][20][256];
  int t = threadIdx.x, lane = t & 63, w = t >> 6;
  int row0 = blockIdx.x*(4*DR) + w*DR;
  float acc[DR][20];
  #pragma unroll
  for (int r=0;r<DR;++r)
    #pragma unroll
    for (int q=0;q<20;++q) acc[r][q]=0.f;

  const float4* xv = (const float4*)x;   // x row k = 5 float4s at k*5
  int nchunk = K >> 8;
  const float* Abase = A + (size_t)row0*K + (lane<<2);

  { // stage chunk 0 (transposed)
    float4 s0[5];
    #pragma unroll
    for (int i=0;i<5;++i) s0[i] = xv[(size_t)t*5 + i];
    #pragma unroll
    for (int i=0;i<5;++i) {
      xs[0][4*i+0][t]=s0[i].x; xs[0][4*i+1][t]=s0[i].y;
      xs[0][4*i+2][t]=s0[i].z; xs[0][4*i+3][t]=s0[i].w;
    }
  }
  float4 a4[DR];                          // A for current chunk
  #pragma unroll
  for (int r=0;r<DR;++r) a4[r] = *(const float4*)(Abase + (size_t)r*K);
  __syncthreads();

  for (int c=0; c<nchunk; ++c) {
    int cur = c & 1;
    bool more = (c+1 < nchunk);
    float4 st[5];
    float4 an[DR];
    if (more) {                           // issue next x-stage + next A loads
      size_t kb = (size_t)(c+1)*256 + t;
      #pragma unroll
      for (int i=0;i<5;++i) st[i] = xv[kb*5 + i];
      const float* An = Abase + (c+1)*256;
      #pragma unroll
      for (int r=0;r<DR;++r) an[r] = *(const float4*)(An + (size_t)r*K);
    }
    #pragma unroll
    for (int q=0;q<20;++q) {
      float4 xq = *(const float4*)(&xs[cur][q][lane<<2]);
      #pragma unroll
      for (int r=0;r<DR;++r) {
        acc[r][q] = fmaf(a4[r].x, xq.x, acc[r][q]);
        acc[r][q] = fmaf(a4[r].y, xq.y, acc[r][q]);
        acc[r][q] = fmaf(a4[r].z, xq.z, acc[r][q]);
        acc[r][q] = fmaf(a4[r].w, xq.w, acc[r][q]);
      }
    }
    if (more) {                           // publish next buffer, rotate A
      #pragma unroll
      for (int i=0;i<5;++i) {
        xs[cur^1][4*i+0][t]=st[i].x; xs[cur^1][4*i+1][t]=st[i].y;
        xs[cur^1][4*i+2][t]=st[i].z; xs[cur^1][4*i+3][t]=st[i].w;
      }
      #pragma unroll
      for (int r=0;r<DR;++r) a4[r] = an[r];
    }
    __syncthreads();
  }

  #pragma unroll
  for (int r=0;r<DR;++r) {
    #pragma unroll
    for (int q=0;q<20;++q) {
      float s = acc[r][q];
      #pragma unroll
      for (int off=32; off; off>>=1) s += __shfl_xor(s, off, 64);
      acc[r][q]=s;
    }
    if (lane==0) {
      float4* yp = (float4*)(y + (size_t)(row0+r)*20);
      yp[0] = make_float4(acc[r][0],acc[r][1],acc[r][2],acc[r][3]);
      yp[1] = make_float4(acc[r][4],acc[r][5],acc[r][6],acc[r][7]);
      yp[2] = make_float4(acc[r][8],acc[r][9],acc[r][10],acc[r][11]);
      yp[3] = make_float4(acc[r][12],acc[r][13],acc[r][14],acc[r][15]);
      yp[4] = make_float4(acc[r][16],acc[r][17],acc[r][18],acc[r][19]);
    }
  }
}

// ---------------- stats partials over a [rows][80] array ----------------
__global__ __launch_bounds__(256) void k_stats(
    const float* __restrict__ src, int rows, float* __restrict__ part)
{
  __shared__ float st[3][2][CC];
  int t = threadIdx.x;
  int c = t % CC, rs = t / CC;
  if (t < 240) {
    float s=0.f,q=0.f;
    for (int row = blockIdx.x*3 + rs; row < rows; row += gridDim.x*3) {
      float val = src[(size_t)row*CC + c];
      s += val; q = fmaf(val,val,q);
    }
    st[rs][0][c]=s; st[rs][1][c]=q;
  }
  __syncthreads();
  if (t < CC) {
    part[(blockIdx.x*2+0)*CC+t]=st[0][0][t]+st[1][0][t]+st[2][0][t];
    part[(blockIdx.x*2+1)*CC+t]=st[0][1][t]+st[1][1][t]+st[2][1][t];
  }
}

// ---------------- fused BN(fold)+FC+ELU+residual, + output-stats partials ----------------
__global__ __launch_bounds__(256) void k_fc(
    const float* __restrict__ p1, const float* __restrict__ p2,
    const float* __restrict__ sp1, int ns1,
    const float* __restrict__ sp2, int ns2,
    const float* __restrict__ g, const float* __restrict__ bb,
    const float* __restrict__ W, const float* __restrict__ cb,
    const float* add, float* out,
    float* __restrict__ statout, int rows, float invrows)
{
  __shared__ float Wl[C2*CC];
  __shared__ float ad[2][C2];
  __shared__ float bpl[CC];
  __shared__ float xsh[3][C2];
  __shared__ float st[3][2][CC];
  int t = threadIdx.x;
  if (t < C2) {
    int c = (t<CC)? t : t-CC;
    const float* sp = (t<CC)? sp1 : sp2;
    int ns = (t<CC)? ns1 : ns2;
    float s=0.f,q=0.f;
    for (int i=0;i<ns;++i){ s += sp[(i*2+0)*CC+c]; q += sp[(i*2+1)*CC+c]; }
    float mean = s*invrows;
    float var  = fmaf(-mean, mean, q*invrows);
    float aa   = g[t]*rsqrtf(var + 1e-5f);
    ad[0][t]=aa; ad[1][t]= bb[t] - mean*aa;
  }
  __syncthreads();
  for (int i=t;i<C2*CC;i+=256) Wl[i] = W[i]*ad[0][i/CC];
  if (t < CC) {
    float s = cb[t];
    for (int c2=0;c2<C2;++c2) s = fmaf(ad[1][c2], W[c2*CC+t], s);
    bpl[t]=s;
  }
  __syncthreads();
  int c = t%CC, rs = t/CC;
  bool act = t < 240;
  float ssum=0.f, ssq=0.f;
  for (int r0 = blockIdx.x*3; r0 < rows; r0 += gridDim.x*3) {
    int row = r0 + rs;
    bool ok = act && row < rows;
    if (ok) {
      xsh[rs][c]    = p1[(size_t)row*CC+c];
      xsh[rs][CC+c] = p2[(size_t)row*CC+c];
    }
    __syncthreads();
    if (ok) {
      float acc = bpl[c];
      #pragma unroll 8
      for (int c2=0;c2<C2;++c2) acc = fmaf(xsh[rs][c2], Wl[c2*CC+c], acc);
      acc = acc>0.f ? acc : expm1f(acc);
      acc += add[(size_t)row*CC+c];
      out[(size_t)row*CC+c] = acc;
      ssum += acc; ssq = fmaf(acc,acc,ssq);
    }
    __syncthreads();
  }
  if (act){ st[rs][0][c]=ssum; st[rs][1][c]=ssq; }
  __syncthreads();
  if (t<CC){
    statout[(blockIdx.x*2+0)*CC+t] = st[0][0][t]+st[1][0][t]+st[2][0][t];
    statout[(blockIdx.x*2+1)*CC+t] = st[0][1][t]+st[1][1][t]+st[2][1][t];
  }
}

// ---------------- final: vf = elu(bn1(v2)+bn2(v1)+bn3(v0)) ----------------
__global__ __launch_bounds__(256) void k_final(
    const float* __restrict__ v2, const float* __restrict__ v1, const float* __restrict__ v0,
    const float* __restrict__ s2, const float* __restrict__ s1, const float* __restrict__ s0,
    const float* __restrict__ g1, const float* __restrict__ b1,
    const float* __restrict__ g2, const float* __restrict__ b2,
    const float* __restrict__ g3, const float* __restrict__ b3,
    float* __restrict__ vf)
{
  __shared__ float A[3][CC], D[3][CC];
  int t = threadIdx.x;
  if (t < 240) {
    int set = t/CC, c = t%CC;
    const float* sp  = set==0? s2 : (set==1? s1 : s0);
    const float* gg  = set==0? g1 : (set==1? g2 : g3);
    const float* bbp = set==0? b1 : (set==1? b2 : b3);
    float s=0.f,q=0.f;
    for (int i=0;i<NSLOT;++i){ s+=sp[(i*2+0)*CC+c]; q+=sp[(i*2+1)*CC+c]; }
    float mean = s*(1.f/ROWS_Y);
    float var  = fmaf(-mean,mean,q*(1.f/ROWS_Y));
    float aa   = gg[c]*rsqrtf(var+1e-5f);
    A[set][c]=aa; D[set][c]=bbp[c]-mean*aa;
  }
  __syncthreads();
  for (size_t idx = (size_t)blockIdx.x*256 + t; idx < (size_t)ROWS_Y*CC; idx += (size_t)gridDim.x*256) {
    int c = (int)(idx % CC);
    float val = fmaf(v2[idx],A[0][c],D[0][c]) + fmaf(v1[idx],A[1][c],D[1][c]) + fmaf(v0[idx],A[2][c],D[2][c]);
    vf[idx] = val>0.f? val : expm1f(val);
  }
}

// ---------------- w[b,n] = sum_k mask[b,k] L[b,k,n] ----------------
__global__ __launch_bounds__(256) void k_w(
    const float* __restrict__ mask, const float* __restrict__ L, float* __restrict__ w)
{
  int bx = blockIdx.x;            // 32
  int b = bx >> 4, n0 = (bx & 15) * 64;
  int t = threadIdx.x;
  int ks = t >> 6;
  __shared__ float red[4][64];
  float acc=0.f;
  const float* Lb = L + (size_t)b*NN*NN;
  const float* mb = mask + b*NN;
  int n = n0 + (t & 63);
  for (int k = ks*256; k < ks*256+256; ++k)
    acc = fmaf(mb[k], Lb[(size_t)k*NN + n], acc);
  red[ks][t&63]=acc;
  __syncthreads();
  if (t < 64) w[b*NN + n0 + t] = red[0][t]+red[1][t]+red[2][t]+red[3][t];
}

// ---------------- pooled partials: p1 = sum mask*vf, p2 = sum w*vf ----------------
__global__ __launch_bounds__(256) void k_pool(
    const float* __restrict__ vf, const float* __restrict__ mask,
    const float* __restrict__ w, float* __restrict__ part)
{
  int bx = blockIdx.x;            // 16
  int b = bx >> 3, slab = bx & 7;
  int t = threadIdx.x, c = t%CC, rs = t/CC;
  __shared__ float st[3][2][CC];
  if (t<240) {
    float a1=0.f,a2=0.f;
    for (int r = rs; r < 128; r += 3) {
      int row = slab*128 + r;
      float val = vf[((size_t)b*NN + row)*CC + c];
      a1 = fmaf(mask[b*NN+row], val, a1);
      a2 = fmaf(w[b*NN+row],    val, a2);
    }
    st[rs][0][c]=a1; st[rs][1][c]=a2;
  }
  __syncthreads();
  if (t<CC) {
    part[((b*8+slab)*2+0)*CC+t] = st[0][0][t]+st[1][0][t]+st[2][0][t];
    part[((b*8+slab)*2+1)*CC+t] = st[0][1][t]+st[1][1][t]+st[2][1][t];
  }
}

// ---------------- out[b,co] = (p1@W0 + p2@W1)/msum + b2 ----------------
__global__ __launch_bounds__(256) void k_out(
    const float* __restrict__ part, const float* __restrict__ mask,
    const float* __restrict__ W0, const float* __restrict__ W1,
    const float* __restrict__ b2, float* __restrict__ outp)
{
  __shared__ float pl[2][2][CC];
  __shared__ float ms[2];
  int t = threadIdx.x;
  if (t < 160) {
    int b = t/CC, c = t%CC;
    float s1=0.f,s2=0.f;
    for (int slab=0; slab<8; ++slab){
      s1 += part[((b*8+slab)*2+0)*CC+c];
      s2 += part[((b*8+slab)*2+1)*CC+c];
    }
    pl[b][0][c]=s1; pl[b][1][c]=s2;
  }
  if (t>=160 && t<162) {
    int b=t-160; float s=0.f;
    for (int k=0;k<NN;++k) s += mask[b*NN+k];
    ms[b]=s;
  }
  __syncthreads();
  int b = t >> 7, co = t & 127;
  float acc = 0.f;
  #pragma unroll 8
  for (int c=0;c<CC;++c)
    acc += pl[b][0][c]*W0[c*128+co] + pl[b][1][c]*W1[c*128+co];
  outp[t] = acc/ms[b] + b2[co];
}

extern "C" void kernel_launch(void* const* d_in, const int* in_sizes, int n_in,
                              void* d_out, int out_size, void* d_ws, size_t ws_size,
                              hipStream_t stream)
{
  const float* inp  = (const float*)d_in[0];
  const float* L    = (const float*)d_in[1];
  const float* Di   = (const float*)d_in[2];
  const float* DiA  = (const float*)d_in[3];
  const float* mask = (const float*)d_in[4];
  const float* c1W0 = (const float*)d_in[5];
  const float* c1W1 = (const float*)d_in[6];
  const float* c1b  = (const float*)d_in[7];
  const float* bn0g = (const float*)d_in[8];
  const float* bn0b = (const float*)d_in[9];
  const float* fc0W = (const float*)d_in[10];
  const float* fc0b = (const float*)d_in[11];
  const float* bn1g = (const float*)d_in[12];
  const float* bn1b = (const float*)d_in[13];
  const float* fc1W = (const float*)d_in[14];
  const float* fc1b = (const float*)d_in[15];
  const float* fbn1g= (const float*)d_in[16];
  const float* fbn1b= (const float*)d_in[17];
  const float* fbn2g= (const float*)d_in[18];
  const float* fbn2b= (const float*)d_in[19];
  const float* fbn3g= (const float*)d_in[20];
  const float* fbn3b= (const float*)d_in[21];
  const float* c2W0 = (const float*)d_in[22];
  const float* c2W1 = (const float*)d_in[23];
  const float* c2b  = (const float*)d_in[24];

  float* ws = (float*)d_ws;
  size_t off = 0;
  auto alloc = [&](size_t n)->float* { float* p = ws + off; off += (n + 63) & ~(size_t)63; return p; };
  float* vb[3];   for (int i=0;i<3;++i) vb[i]   = alloc((size_t)BB*NN*CC);
  float* fb[2];   for (int i=0;i<2;++i) fb[i]   = alloc((size_t)BB*FF*CC);
  float* Dv       = alloc((size_t)BB*FF*CC);
  float* Df       = alloc((size_t)BB*NN*CC);
  float* vstat[3];for (int i=0;i<3;++i) vstat[i]= alloc((size_t)NSLOT*2*CC);
  float* fstat[2];for (int i=0;i<2;++i) fstat[i]= alloc((size_t)NSLOT*2*CC);
  float* dvstat   = alloc((size_t)NSLOT*2*CC);
  float* dfstat   = alloc((size_t)NSLOT*2*CC);
  float* vf       = alloc((size_t)BB*NN*CC);
  float* wv       = alloc((size_t)BB*NN);
  float* part     = alloc((size_t)16*2*CC);

  hipMemsetAsync(fb[0],    0, (size_t)BB*FF*CC*4, stream);
  hipMemsetAsync(fb[1],    0, (size_t)BB*FF*CC*4, stream);
  hipMemsetAsync(vb[1],    0, (size_t)BB*NN*CC*4, stream);
  hipMemsetAsync(fstat[0], 0, (size_t)NSLOT*2*CC*4, stream);

  k_conv1<<<128,256,0,stream>>>(inp, L, c1W0, c1W1, c1b, vb[0], vstat[0]);

  int cur=0, p1=1, p2=2, fcur=0, fs=0;
  for (int it=0; it<NB_; ++it) {
    k_dirac<4><<<dim3(512,2),256,0,stream>>>(Di, vb[cur], Dv, 4*FF, 4*NN);
    k_stats<<<128,256,0,stream>>>(Dv, ROWS_X, dvstat);
    k_fc<<<128,256,0,stream>>>(fb[fcur], Dv, fstat[fs],NSLOT, dvstat,NSLOT,
        bn0g+(size_t)it*C2, bn0b+(size_t)it*C2, fc0W+(size_t)it*C2*CC, fc0b+(size_t)it*CC,
        fb[1-fcur], fb[1-fcur], fstat[1-fs], ROWS_X, 1.f/ROWS_X);
    fcur = 1-fcur; fs = 1-fs;
    k_dirac<4><<<dim3(256,2),256,0,stream>>>(DiA, fb[fcur], Df, 4*NN, 4*FF);
    k_stats<<<128,256,0,stream>>>(Df, ROWS_Y, dfstat);
    k_fc<<<128,256,0,stream>>>(vb[cur], Df, vstat[cur],NSLOT, dfstat,NSLOT,
        bn1g+(size_t)it*C2, bn1b+(size_t)it*C2, fc1W+(size_t)it*C2*CC, fc1b+(size_t)it*CC,
        vb[p1], vb[p2], vstat[p2], ROWS_Y, 1.f/ROWS_Y);
    int tmp=p2; p2=p1; p1=cur; cur=tmp;
  }

  k_final<<<128,256,0,stream>>>(vb[cur],vb[p1],vb[p2], vstat[cur],vstat[p1],vstat[p2],
      fbn1g,fbn1b,fbn2g,fbn2b,fbn3g,fbn3b, vf);
  k_w<<<32,256,0,stream>>>(mask, L, wv);
  k_pool<<<16,256,0,stream>>>(vf, mask, wv, part);
  k_out<<<1,256,0,stream>>>(part, mask, c2W0, c2W1, c2b, (float*)d_out);
}